// Round 17
// baseline (673.517 us; speedup 1.0000x reference)
//
#include <hip/hip_runtime.h>
#include <math.h>

// Problem constants
#define B 4
#define Q 75
#define NBQ (B*Q)        // 300
#define NWAY 5
#define KSHOT 5
#define C 640
#define HW 100
#define MS 500
#define SLAB (C*HW)      // 64000 floats

// GEMM geometry: M = 7500 padded to 7552 rows per b; 32-row tiles -> 236/b.
// K = 640 (20 k-steps of 32). Cols per (b,n): 500 -> 512.
#define MT32_B 236
#define RT_B 472                  // 16-row frags per b
#define A_CHUNKS_B (RT_B*20*64)   // 604160 uint4 chunks per b (per split)
#define S_CHUNKS_ALL (20*32*20*64)   // 819200 chunks (all 20 bn, per split)
#define S_CHUNKS_B   (5*32*20*64)    // 204800 chunks (5 bn, per split)

// Numerics (PROVEN absmax=0 in r12-r16): f16 2-limb split, 3 products.
// Conv: w = 16*v; h0 = f16(w); h1 = f16((w - h0)*2048).
//   acc0 += h0a*h0b ; accM += h0a*h1b + h1a*h0b
//   simi = acc0/256 + accM/(256*2048)    (exact power-of-2 combine)
#define CHI 0.00390625f              // 1/256
#define CLO 1.9073486328125e-06f     // 1/(256*2048)

typedef _Float16 half8 __attribute__((ext_vector_type(8)));
typedef float f32x4 __attribute__((ext_vector_type(4)));

// ws layout (float offsets):
//   invs 0 (10000) | invq 10000 (30000) | cmax 40000 (150000)
//   carg 190000 (150000 int) | lossv 340000 -> base 340352
#define WS_BASE 340352ull
#define NEED_ALL   104908288ull
#define NEED_PERB   46908928ull
#define NEED_PERB2  27248128ull

// ---------------------------------------------------------------------------
// K1: per-descriptor inverse L2 norm (fp32). 400 blocks.
// ---------------------------------------------------------------------------
__global__ __launch_bounds__(256) void norm_kernel(const float* __restrict__ s_xf,
                                                   const float* __restrict__ q_xf,
                                                   float* __restrict__ invs,
                                                   float* __restrict__ invq) {
  int id = blockIdx.x;
  const float* base;
  float* out;
  if (id < 100) { base = s_xf + (size_t)id * SLAB;        out = invs + id * HW; }
  else          { base = q_xf + (size_t)(id - 100) * SLAB; out = invq + (id - 100) * HW; }
  __shared__ float ssum[2][HW];
  int t = threadIdx.x;
  if (t < 2 * HW) ((float*)ssum)[t] = 0.f;
  __syncthreads();
  if (t < 2 * HW) {
    int p = t % HW, half = t / HW;
    float part = 0.f;
    for (int ch = half * 320; ch < half * 320 + 320; ++ch) {
      float v = base[ch * HW + p];
      part = fmaf(v, v, part);
    }
    ssum[half][p] = part;
  }
  __syncthreads();
  if (t < HW) {
    float nrm = sqrtf(ssum[0][t] + ssum[1][t]);
    out[t] = 1.f / fmaxf(nrm, 1e-12f);
  }
}

__device__ __forceinline__ void dual_split(float w, _Float16* h0, _Float16* h1) {
  _Float16 a = (_Float16)w;
  *h0 = a;
  *h1 = (_Float16)((w - (float)a) * 2048.f);
}

// ---------------------------------------------------------------------------
// K2a: support -> normalized x16-scaled f16 2-limb split in fragment order.
// chunk id = ((bnl*32 + jf)*20 + ks)*64 + lane ; 8 halves along k per chunk.
// ---------------------------------------------------------------------------
__global__ __launch_bounds__(256) void convs_kernel(const float* __restrict__ s_xf,
                                                    const float* __restrict__ invs,
                                                    uint4* __restrict__ o0,
                                                    uint4* __restrict__ o1,
                                                    int bn0) {
  int id = blockIdx.x * 256 + threadIdx.x;
  int lane = id & 63;
  int tmp = id >> 6;
  int ks = tmp % 20;
  int t2 = tmp / 20;
  int jf = t2 % 32;
  int bnl = t2 / 32;
  int bn = bn0 + bnl;
  int j = jf * 16 + (lane & 15);
  int k = ks * 32 + (lane >> 4) * 8;
  union { _Float16 h[8]; uint4 u; } p0, p1;
  if (j < MS) {
    int s = j / 100, p = j % 100;
    int slab = bn * 5 + s;                        // b*25 + n*5 + s
    const float* src = s_xf + ((size_t)slab * 640 + k) * 100 + p;
    float sc = invs[slab * 100 + p] * 16.f;
#pragma unroll
    for (int kj = 0; kj < 8; ++kj)
      dual_split(src[kj * 100] * sc, &p0.h[kj], &p1.h[kj]);
  } else {
    p0.u = make_uint4(0, 0, 0, 0);
    p1.u = make_uint4(0, 0, 0, 0);
  }
  o0[id] = p0.u; o1[id] = p1.u;
}

// ---------------------------------------------------------------------------
// K2b: query -> normalized x16-scaled f16 2-limb split in fragment order.
// ---------------------------------------------------------------------------
__global__ __launch_bounds__(256) void convq_kernel(const float* __restrict__ q_xf,
                                                    const float* __restrict__ invq,
                                                    uint4* __restrict__ o0,
                                                    uint4* __restrict__ o1,
                                                    int b0) {
  int id = blockIdx.x * 256 + threadIdx.x;
  int bloc = id / A_CHUNKS_B;
  int c = id % A_CHUNKS_B;
  int bb = b0 + bloc;
  int lane = c & 63;
  int tmp = c >> 6;
  int ks = tmp % 20;
  int rt = tmp / 20;
  int row = rt * 16 + (lane & 15);
  int k = ks * 32 + (lane >> 4) * 8;
  union { _Float16 h[8]; uint4 u; } p0, p1;
  if (row < Q * HW) {
    int qi = row / 100, p = row % 100;
    const float* src = q_xf + ((size_t)(bb * Q + qi) * 640 + k) * 100 + p;
    float sc = invq[(bb * Q + qi) * 100 + p] * 16.f;
#pragma unroll
    for (int kj = 0; kj < 8; ++kj)
      dual_split(src[kj * 100] * sc, &p0.h[kj], &p1.h[kj]);
  } else {
    p0.u = make_uint4(0, 0, 0, 0);
    p1.u = make_uint4(0, 0, 0, 0);
  }
  o0[id] = p0.u; o1[id] = p1.u;
}

// ---------------------------------------------------------------------------
// K3: f16 2-limb MFMA GEMM (3 products) + fused per-class max/argmax.
// BARRIER-FREE K-LOOP (r16 lesson): the per-k-step __syncthreads existed only
// because A transited LDS; A is stored in fragment order, so each wave loads
// its own A fragments straight to VGPRs (4x16B/lane coalesced; the 4x
// intra-block redundancy is L2-absorbed). Zero LDS staging, zero barriers in
// the K loop -> compiler emits COUNTED vmcnt waits on true deps only, waves
// fully independent, latency hidden by TLP (3 waves/SIMD).
// 256 thr / 4 waves; block tile 32 rows x 512 cols (2 col-passes);
// wave tile 2mf x 4f; acc 64 regs, total ~135 regs.
// B direct global->VGPR (L2-resident via bn-major chunked XCD swizzle).
// ---------------------------------------------------------------------------
__global__ __launch_bounds__(256, 3) void gemm_kernel(
    const uint4* __restrict__ a0, const uint4* __restrict__ a1,
    const uint4* __restrict__ b0p, const uint4* __restrict__ b1p,
    float* __restrict__ cmax, int* __restrict__ carg,
    int bq0, int aStride, int sbnBase, int mode /*0=ALL(4720), 1=per-b(1180)*/) {
  // chunked XCD swizzle over bn-major order
  int wgid = blockIdx.x;
  int x = wgid & 7, s = wgid >> 3;
  int o;
  if (mode == 0) {               // 4720 = 8*590 exact
    o = x * 590 + s;
  } else {                       // 1180 = 4*148 + 4*147, launch 1184
    if (x < 4) { if (s >= 148) return; o = x * 148 + s; }
    else       { if (s >= 147) return; o = 592 + (x - 4) * 147 + s; }
  }
  int bnloc = o / MT32_B;        // bn-major: consecutive blocks share bn
  int mt32 = o % MT32_B;
  int bloc = bnloc / 5;
  int n = bnloc % 5;
  int bb = bq0 + bloc;
  const uint4* A0 = a0 + (size_t)bloc * aStride;
  const uint4* A1 = a1 + (size_t)bloc * aStride;
  int bnl = bb * 5 + n - sbnBase;

  __shared__ float sV[4][32];
  __shared__ int   sJ[4][32];

  int t = threadIdx.x;
  int w = t >> 6, lane = t & 63;        // w = jw, 0..3

  if (lane < 32) { sV[w][lane] = -1e30f; sJ[w][lane] = 0; }

  // A fragment base for this block: rt = mt32*2 + rtl, chunk (rt*20+ks)*64+lane
  size_t aBase = ((size_t)(mt32 * 2) * 20) * 64 + lane;   // + rtl*1280 + ks*64

  for (int pass = 0; pass < 2; ++pass) {
    int jf0 = pass * 16 + w * 4;        // this wave's first jf frag
    size_t bBase = (size_t)(bnl * 32 + jf0) * 1280 + lane;  // 20 ks * 64

    f32x4 acc0[2][4], accM[2][4];
#pragma unroll
    for (int mf = 0; mf < 2; ++mf)
#pragma unroll
      for (int f = 0; f < 4; ++f) {
        acc0[mf][f] = (f32x4){0.f, 0.f, 0.f, 0.f};
        accM[mf][f] = (f32x4){0.f, 0.f, 0.f, 0.f};
      }

#pragma unroll 1                       // keep one k-step's loads live (r14)
    for (int ks = 0; ks < 20; ++ks) {
      size_t ao = aBase + (size_t)ks * 64;
      half8 a0v[2], a1v[2];            // [rtl] for limb0 / limb1
      a0v[0] = *(const half8*)&A0[ao];
      a0v[1] = *(const half8*)&A0[ao + 1280];
      a1v[0] = *(const half8*)&A1[ao];
      a1v[1] = *(const half8*)&A1[ao + 1280];

      size_t bo = bBase + (size_t)ks * 64;
      half8 bv0[4], bv1[4];
#pragma unroll
      for (int f = 0; f < 4; ++f) bv0[f] = *(const half8*)&b0p[bo + (size_t)f * 1280];
#pragma unroll
      for (int f = 0; f < 4; ++f) bv1[f] = *(const half8*)&b1p[bo + (size_t)f * 1280];

#pragma unroll
      for (int mf = 0; mf < 2; ++mf) {
#pragma unroll
        for (int f = 0; f < 4; ++f) {
          acc0[mf][f] = __builtin_amdgcn_mfma_f32_16x16x32_f16(a0v[mf], bv0[f], acc0[mf][f], 0, 0, 0);
          accM[mf][f] = __builtin_amdgcn_mfma_f32_16x16x32_f16(a0v[mf], bv1[f], accM[mf][f], 0, 0, 0);
          accM[mf][f] = __builtin_amdgcn_mfma_f32_16x16x32_f16(a1v[mf], bv0[f], accM[mf][f], 0, 0, 0);
        }
      }
    }

    // fold this pass into LDS running argmax (j ascends with pass; strict >)
#pragma unroll
    for (int mf = 0; mf < 2; ++mf)
#pragma unroll
      for (int f = 0; f < 4; ++f) {
        int j = pass * 256 + w * 64 + f * 16 + (lane & 15);
        bool ok = (j < MS);
#pragma unroll
        for (int rg = 0; rg < 4; ++rg) {
          float v = ok ? (acc0[mf][f][rg] * CHI + accM[mf][f][rg] * CLO) : -1e30f;
          int ji = ok ? j : 0x7fffffff;
#pragma unroll
          for (int mk = 1; mk < 16; mk <<= 1) {
            float ov = __shfl_xor(v, mk);
            int oj = __shfl_xor(ji, mk);
            if (ov > v || (ov == v && oj < ji)) { v = ov; ji = oj; }
          }
          if ((lane & 15) == 0) {
            int row32 = mf * 16 + (lane >> 4) * 4 + rg;
            if (v > sV[w][row32]) { sV[w][row32] = v; sJ[w][row32] = ji; }
          }
        }
      }
  }

  __syncthreads();
  // combine the 4 jw partials per row; single writer per row (wave 0)
  if (w == 0 && lane < 32) {
    int row32 = lane;
    float v = sV[0][row32];
    int ji = sJ[0][row32];
#pragma unroll
    for (int q4 = 1; q4 < 4; ++q4) {
      float ov = sV[q4][row32];
      int oj = sJ[q4][row32];
      if (ov > v || (ov == v && oj < ji)) { v = ov; ji = oj; }
    }
    int r = mt32 * 32 + row32;
    if (r < Q * HW) {
      int bq = bb * Q + r / 100, p = r % 100;
      size_t oo = (size_t)(bq * NWAY + n) * HW + p;
      cmax[oo] = v;
      carg[oo] = ji;
    }
  }
}

// ---------------------------------------------------------------------------
// Fallback fp32 simi kernel (used only if ws too small) — known-good.
// ---------------------------------------------------------------------------
#define TCF 32
#define TJF 64
__global__ __launch_bounds__(256) void simi_kernel(const float* __restrict__ s_xf,
                                                   const float* __restrict__ q_xf,
                                                   const float* __restrict__ invs,
                                                   const float* __restrict__ invq,
                                                   float* __restrict__ cmax,
                                                   int* __restrict__ carg) {
  int id = blockIdx.x;
  int n = id % NWAY;
  int bq = id / NWAY;
  int b = bq / Q;
  const float* qbase = q_xf + (size_t)bq * SLAB;
  const float* sbase = s_xf + (size_t)(b * 25 + n * KSHOT) * SLAB;
  const float* invqB = invq + bq * HW;
  const float* invsB = invs + (b * 2500 + n * MS);

  __shared__ __align__(16) float As[TCF][112];
  __shared__ __align__(16) float Bs[TCF][TJF];
  __shared__ float sInvQ[HW];
  __shared__ float sInvS[MS];

  int t = threadIdx.x;
  for (int i = t; i < HW; i += 256) sInvQ[i] = invqB[i];
  for (int i = t; i < MS; i += 256) sInvS[i] = invsB[i];

  int tj = t & 15, tm = t >> 4;
  float best[7];
  int bidx[7];
#pragma unroll
  for (int r = 0; r < 7; ++r) { best[r] = -1e30f; bidx[r] = 0; }

  for (int jt0 = 0; jt0 < MS; jt0 += TJF) {
    float acc[7][4];
#pragma unroll
    for (int r = 0; r < 7; ++r)
#pragma unroll
      for (int jj = 0; jj < 4; ++jj) acc[r][jj] = 0.f;
    for (int c0 = 0; c0 < C; c0 += TCF) {
      __syncthreads();
      for (int i = t; i < TCF * HW; i += 256) {
        int p = i % HW;
        As[i / HW][p] = qbase[c0 * HW + i] * sInvQ[p];
      }
      for (int i = t; i < TCF * TJF; i += 256) {
        int cc = i / TJF, jj = i % TJF;
        int j = jt0 + jj;
        float v = 0.f;
        if (j < MS) v = sbase[(j / 100) * SLAB + (c0 + cc) * 100 + (j % 100)] * sInvS[j];
        Bs[cc][jj] = v;
      }
      __syncthreads();
#pragma unroll
      for (int cc = 0; cc < TCF; ++cc) {
        float4 bv = *(const float4*)&Bs[cc][tj * 4];
#pragma unroll
        for (int r = 0; r < 7; ++r) {
          float a = As[cc][tm * 7 + r];
          acc[r][0] = fmaf(a, bv.x, acc[r][0]);
          acc[r][1] = fmaf(a, bv.y, acc[r][1]);
          acc[r][2] = fmaf(a, bv.z, acc[r][2]);
          acc[r][3] = fmaf(a, bv.w, acc[r][3]);
        }
      }
    }
#pragma unroll
    for (int r = 0; r < 7; ++r)
#pragma unroll
      for (int jj = 0; jj < 4; ++jj) {
        int j = jt0 + tj * 4 + jj;
        float v = acc[r][jj];
        if (j < MS && v > best[r]) { best[r] = v; bidx[r] = j; }
      }
  }
#pragma unroll
  for (int r = 0; r < 7; ++r)
#pragma unroll
    for (int mask = 1; mask < 16; mask <<= 1) {
      float ov = __shfl_xor(best[r], mask);
      int oi = __shfl_xor(bidx[r], mask);
      if (ov > best[r] || (ov == best[r] && oi < bidx[r])) { best[r] = ov; bidx[r] = oi; }
    }
  if (tj == 0)
#pragma unroll
    for (int r = 0; r < 7; ++r) {
      int m = tm * 7 + r;
      if (m < HW) {
        cmax[(size_t)(bq * NWAY + n) * HW + m] = best[r];
        carg[(size_t)(bq * NWAY + n) * HW + m] = bidx[r];
      }
    }
}

// ---------------------------------------------------------------------------
// K4: per-(b,qi) DMNN mask + query_value + per-query loss.
// ---------------------------------------------------------------------------
__global__ __launch_bounds__(128) void mask_loss_kernel(const float* __restrict__ cmax,
                                                        const int* __restrict__ carg,
                                                        const int* __restrict__ query_y,
                                                        float* __restrict__ lossv) {
  int bq = blockIdx.x;
  int t = threadIdx.x;
  __shared__ float sDiff[HW];
  __shared__ int sNear[HW];
  __shared__ float sCm[NWAY][HW];
  __shared__ float red[128];

  if (t < HW) {
    float cm[NWAY];
#pragma unroll
    for (int nn = 0; nn < NWAY; ++nn) {
      cm[nn] = cmax[(size_t)(bq * NWAY + nn) * HW + t];
      sCm[nn][t] = cm[nn];
    }
    float v0 = -1e30f, v1 = -1e30f;
#pragma unroll
    for (int nn = 0; nn < NWAY; ++nn) {
      float v = cm[nn];
      if (v > v0) { v1 = v0; v0 = v; }
      else if (v > v1) { v1 = v; }
    }
    sDiff[t] = v0 - v1;
    float gb = -1e30f;
    int gn = 0;
#pragma unroll
    for (int nn = 0; nn < NWAY; ++nn)
      if (cm[nn] > gb) { gb = cm[nn]; gn = nn; }
    sNear[t] = gn * MS + carg[(size_t)(bq * NWAY + gn) * HW + t];
  }
  __syncthreads();

  bool msk = false;
  if (t < HW) {
    int j = sNear[t];
    int wn = 0;
    float wv = -1.f;
    for (int mp = 0; mp < HW; ++mp) {
      float v = (sNear[mp] == j) ? sDiff[mp] : 0.f;
      if (v > wv) { wv = v; wn = mp; }
    }
    msk = (wn == t);
  }

  float qv[NWAY];
#pragma unroll
  for (int nn = 0; nn < NWAY; ++nn) {
    __syncthreads();
    red[t] = (t < HW && msk) ? sCm[nn][t] : 0.f;
    __syncthreads();
    for (int s = 64; s > 0; s >>= 1) {
      if (t < s) red[t] += red[t + s];
      __syncthreads();
    }
    qv[nn] = red[0];
  }

  if (t == 0) {
    float logits[NWAY], mx = -1e30f;
#pragma unroll
    for (int nn = 0; nn < NWAY; ++nn) {
      logits[nn] = qv[nn] / 0.2f;
      mx = fmaxf(mx, logits[nn]);
    }
    float se = 0.f;
#pragma unroll
    for (int nn = 0; nn < NWAY; ++nn) se += expf(logits[nn] - mx);
    float lse = mx + logf(se);
    int label = query_y[bq];
    lossv[bq] = -(logits[label] - lse);
  }
}

__global__ __launch_bounds__(512) void finalize_kernel(const float* __restrict__ lossv,
                                                       float* __restrict__ out) {
  __shared__ float red[512];
  int t = threadIdx.x;
  red[t] = (t < NBQ) ? lossv[t] : 0.f;
  __syncthreads();
  for (int s = 256; s > 0; s >>= 1) {
    if (t < s) red[t] += red[t + s];
    __syncthreads();
  }
  if (t == 0) out[0] = red[0] / (float)NBQ;
}

extern "C" void kernel_launch(void* const* d_in, const int* in_sizes, int n_in,
                              void* d_out, int out_size, void* d_ws, size_t ws_size,
                              hipStream_t stream) {
  const float* s_xf = (const float*)d_in[0];
  const float* q_xf = (const float*)d_in[2];
  const int* query_y = (const int*)d_in[3];

  float* ws = (float*)d_ws;
  float* invs = ws;
  float* invq = ws + 10000;
  float* cmax = ws + 40000;
  int* carg = (int*)(ws + 190000);
  float* lossv = ws + 340000;

  norm_kernel<<<400, 256, 0, stream>>>(s_xf, q_xf, invs, invq);

  const size_t SP_ALL = 3276800, SP_B = 819200, QS_B = 2416640;

  if (ws_size >= NEED_ALL) {
    uint4* S0 = (uint4*)(ws + WS_BASE);
    uint4* S1 = (uint4*)(ws + WS_BASE + SP_ALL);
    uint4* Q0 = (uint4*)(ws + WS_BASE + 2 * SP_ALL);
    uint4* Q1 = (uint4*)(ws + WS_BASE + 2 * SP_ALL + 4 * QS_B);
    convs_kernel<<<S_CHUNKS_ALL / 256, 256, 0, stream>>>(s_xf, invs, S0, S1, 0);
    convq_kernel<<<4 * A_CHUNKS_B / 256, 256, 0, stream>>>(q_xf, invq, Q0, Q1, 0);
    gemm_kernel<<<4720, 256, 0, stream>>>(Q0, Q1, S0, S1,
                                          cmax, carg, 0, A_CHUNKS_B, 0, 0);
  } else if (ws_size >= NEED_PERB) {
    uint4* S0 = (uint4*)(ws + WS_BASE);
    uint4* S1 = (uint4*)(ws + WS_BASE + SP_ALL);
    uint4* Q0 = (uint4*)(ws + WS_BASE + 2 * SP_ALL);
    uint4* Q1 = (uint4*)(ws + WS_BASE + 2 * SP_ALL + QS_B);
    convs_kernel<<<S_CHUNKS_ALL / 256, 256, 0, stream>>>(s_xf, invs, S0, S1, 0);
    for (int b = 0; b < 4; ++b) {
      convq_kernel<<<A_CHUNKS_B / 256, 256, 0, stream>>>(q_xf, invq, Q0, Q1, b);
      gemm_kernel<<<1184, 256, 0, stream>>>(Q0, Q1, S0, S1,
                                            cmax, carg, b, 0, 0, 1);
    }
  } else if (ws_size >= NEED_PERB2) {
    uint4* S0 = (uint4*)(ws + WS_BASE);
    uint4* S1 = (uint4*)(ws + WS_BASE + SP_B);
    uint4* Q0 = (uint4*)(ws + WS_BASE + 2 * SP_B);
    uint4* Q1 = (uint4*)(ws + WS_BASE + 2 * SP_B + QS_B);
    for (int b = 0; b < 4; ++b) {
      convs_kernel<<<S_CHUNKS_B / 256, 256, 0, stream>>>(s_xf, invs, S0, S1, b * 5);
      convq_kernel<<<A_CHUNKS_B / 256, 256, 0, stream>>>(q_xf, invq, Q0, Q1, b);
      gemm_kernel<<<1184, 256, 0, stream>>>(Q0, Q1, S0, S1,
                                            cmax, carg, b, 0, b * 5, 1);
    }
  } else {
    simi_kernel<<<1500, 256, 0, stream>>>(s_xf, q_xf, invs, invq, cmax, carg);
  }

  mask_loss_kernel<<<NBQ, 128, 0, stream>>>(cmax, carg, query_y, lossv);
  finalize_kernel<<<1, 512, 0, stream>>>(lossv, (float*)d_out);
}

// Round 18
// 541.036 us; speedup vs baseline: 1.2449x; 1.2449x over previous
//
#include <hip/hip_runtime.h>
#include <math.h>

// Problem constants
#define B 4
#define Q 75
#define NBQ (B*Q)        // 300
#define NWAY 5
#define KSHOT 5
#define C 640
#define HW 100
#define MS 500
#define SLAB (C*HW)      // 64000 floats

// GEMM geometry: M = 7500 padded to 7552 rows per b; 32-row tiles -> 236/b.
// K = 640 (20 k-steps of 32). Cols per (b,n): 500 -> 512.
#define MT32_B 236
#define RT_B 472                  // 16-row frags per b
#define A_CHUNKS_B (RT_B*20*64)   // 604160 uint4 chunks per b (per split)
#define S_CHUNKS_ALL (20*32*20*64)   // 819200 chunks (all 20 bn, per split)
#define S_CHUNKS_B   (5*32*20*64)    // 204800 chunks (5 bn, per split)

// Numerics (PROVEN absmax=0 in r12-r17): f16 2-limb split, 3 products.
// Conv: w = 16*v; h0 = f16(w); h1 = f16((w - h0)*2048).
//   acc0 += h0a*h0b ; accM += h0a*h1b + h1a*h0b
//   simi = acc0/256 + accM/(256*2048)    (exact power-of-2 combine)
#define CHI 0.00390625f              // 1/256
#define CLO 1.9073486328125e-06f     // 1/(256*2048)

typedef _Float16 half8 __attribute__((ext_vector_type(8)));
typedef float f32x4 __attribute__((ext_vector_type(4)));

__device__ __forceinline__ void gl_lds16(const void* gsrc, void* ldst) {
  __builtin_amdgcn_global_load_lds(
      (const __attribute__((address_space(1))) unsigned int*)gsrc,
      (__attribute__((address_space(3))) unsigned int*)ldst, 16, 0, 0);
}

// ws layout (float offsets):
//   invs 0 (10000) | invq 10000 (30000) | cmax 40000 (150000)
//   carg 190000 (150000 int) | lossv 340000 -> base 340352
#define WS_BASE 340352ull
#define NEED_ALL   104908288ull
#define NEED_PERB   46908928ull
#define NEED_PERB2  27248128ull

// ---------------------------------------------------------------------------
// K1: per-descriptor inverse L2 norm (fp32). 400 blocks.
// ---------------------------------------------------------------------------
__global__ __launch_bounds__(256) void norm_kernel(const float* __restrict__ s_xf,
                                                   const float* __restrict__ q_xf,
                                                   float* __restrict__ invs,
                                                   float* __restrict__ invq) {
  int id = blockIdx.x;
  const float* base;
  float* out;
  if (id < 100) { base = s_xf + (size_t)id * SLAB;        out = invs + id * HW; }
  else          { base = q_xf + (size_t)(id - 100) * SLAB; out = invq + (id - 100) * HW; }
  __shared__ float ssum[2][HW];
  int t = threadIdx.x;
  if (t < 2 * HW) ((float*)ssum)[t] = 0.f;
  __syncthreads();
  if (t < 2 * HW) {
    int p = t % HW, half = t / HW;
    float part = 0.f;
    for (int ch = half * 320; ch < half * 320 + 320; ++ch) {
      float v = base[ch * HW + p];
      part = fmaf(v, v, part);
    }
    ssum[half][p] = part;
  }
  __syncthreads();
  if (t < HW) {
    float nrm = sqrtf(ssum[0][t] + ssum[1][t]);
    out[t] = 1.f / fmaxf(nrm, 1e-12f);
  }
}

__device__ __forceinline__ void dual_split(float w, _Float16* h0, _Float16* h1) {
  _Float16 a = (_Float16)w;
  *h0 = a;
  *h1 = (_Float16)((w - (float)a) * 2048.f);
}

// ---------------------------------------------------------------------------
// K2a: support -> normalized x16-scaled f16 2-limb split in fragment order.
// chunk id = ((bnl*32 + jf)*20 + ks)*64 + lane ; 8 halves along k per chunk.
// ---------------------------------------------------------------------------
__global__ __launch_bounds__(256) void convs_kernel(const float* __restrict__ s_xf,
                                                    const float* __restrict__ invs,
                                                    uint4* __restrict__ o0,
                                                    uint4* __restrict__ o1,
                                                    int bn0) {
  int id = blockIdx.x * 256 + threadIdx.x;
  int lane = id & 63;
  int tmp = id >> 6;
  int ks = tmp % 20;
  int t2 = tmp / 20;
  int jf = t2 % 32;
  int bnl = t2 / 32;
  int bn = bn0 + bnl;
  int j = jf * 16 + (lane & 15);
  int k = ks * 32 + (lane >> 4) * 8;
  union { _Float16 h[8]; uint4 u; } p0, p1;
  if (j < MS) {
    int s = j / 100, p = j % 100;
    int slab = bn * 5 + s;                        // b*25 + n*5 + s
    const float* src = s_xf + ((size_t)slab * 640 + k) * 100 + p;
    float sc = invs[slab * 100 + p] * 16.f;
#pragma unroll
    for (int kj = 0; kj < 8; ++kj)
      dual_split(src[kj * 100] * sc, &p0.h[kj], &p1.h[kj]);
  } else {
    p0.u = make_uint4(0, 0, 0, 0);
    p1.u = make_uint4(0, 0, 0, 0);
  }
  o0[id] = p0.u; o1[id] = p1.u;
}

// ---------------------------------------------------------------------------
// K2b: query -> normalized x16-scaled f16 2-limb split in fragment order.
// ---------------------------------------------------------------------------
__global__ __launch_bounds__(256) void convq_kernel(const float* __restrict__ q_xf,
                                                    const float* __restrict__ invq,
                                                    uint4* __restrict__ o0,
                                                    uint4* __restrict__ o1,
                                                    int b0) {
  int id = blockIdx.x * 256 + threadIdx.x;
  int bloc = id / A_CHUNKS_B;
  int c = id % A_CHUNKS_B;
  int bb = b0 + bloc;
  int lane = c & 63;
  int tmp = c >> 6;
  int ks = tmp % 20;
  int rt = tmp / 20;
  int row = rt * 16 + (lane & 15);
  int k = ks * 32 + (lane >> 4) * 8;
  union { _Float16 h[8]; uint4 u; } p0, p1;
  if (row < Q * HW) {
    int qi = row / 100, p = row % 100;
    const float* src = q_xf + ((size_t)(bb * Q + qi) * 640 + k) * 100 + p;
    float sc = invq[(bb * Q + qi) * 100 + p] * 16.f;
#pragma unroll
    for (int kj = 0; kj < 8; ++kj)
      dual_split(src[kj * 100] * sc, &p0.h[kj], &p1.h[kj]);
  } else {
    p0.u = make_uint4(0, 0, 0, 0);
    p1.u = make_uint4(0, 0, 0, 0);
  }
  o0[id] = p0.u; o1[id] = p1.u;
}

// ---------------------------------------------------------------------------
// K3: f16 2-limb MFMA GEMM (3 products) + fused per-class max/argmax.
// r16 structure (best known: LDS A dbuf, per-ks barrier, 3 waves/SIMD) plus
// 2-DEEP B SOFTWARE PIPELINE (r17 lesson: B had zero lookahead; its ~250cyc
// L2 latency sat on every k-step's critical path). Two named B register sets
// (bE even / bO odd), manually unrolled even/odd steps: each step's B loads
// are issued one step早 and complete during the prior MFMA block + barrier.
// 256 thr / 4 waves; block tile 32 rows x 512 cols (2 col-passes);
// wave tile 2mf x 4f; acc 64 regs; B 64 regs. bn-major chunked XCD swizzle.
// ---------------------------------------------------------------------------
__global__ __launch_bounds__(256, 3) void gemm_kernel(
    const uint4* __restrict__ a0, const uint4* __restrict__ a1,
    const uint4* __restrict__ b0p, const uint4* __restrict__ b1p,
    float* __restrict__ cmax, int* __restrict__ carg,
    int bq0, int aStride, int sbnBase, int mode /*0=ALL(4720), 1=per-b(1180)*/) {
  // chunked XCD swizzle over bn-major order
  int wgid = blockIdx.x;
  int x = wgid & 7, s = wgid >> 3;
  int o;
  if (mode == 0) {               // 4720 = 8*590 exact
    o = x * 590 + s;
  } else {                       // 1180 = 4*148 + 4*147, launch 1184
    if (x < 4) { if (s >= 148) return; o = x * 148 + s; }
    else       { if (s >= 147) return; o = 592 + (x - 4) * 147 + s; }
  }
  int bnloc = o / MT32_B;        // bn-major: consecutive blocks share bn
  int mt32 = o % MT32_B;
  int bloc = bnloc / 5;
  int n = bnloc % 5;
  int bb = bq0 + bloc;
  const uint4* A0 = a0 + (size_t)bloc * aStride;
  const uint4* A1 = a1 + (size_t)bloc * aStride;
  int bnl = bb * 5 + n - sbnBase;

  // [buf][limb][rtl][lane*8] -> 8192 B
  __shared__ __align__(16) _Float16 sA[2][2][2][512];
  __shared__ float sV[4][32];
  __shared__ int   sJ[4][32];

  int t = threadIdx.x;
  int w = t >> 6, lane = t & 63;        // w = jw, 0..3

  if (lane < 32) { sV[w][lane] = -1e30f; sJ[w][lane] = 0; }

// stage one 32-wide k-step: wave w stages (limb=w>>1, rtl=w&1) = 1 gl_lds
#define STAGE_A1(KS, BUF) do {                                                  \
    int limb_ = w >> 1, rtl_ = w & 1;                                           \
    size_t aIdx = ((size_t)(mt32 * 2 + rtl_) * 20 + (KS)) * 64 + lane;          \
    gl_lds16((limb_ ? A1 : A0) + aIdx, (void*)&sA[(BUF)][limb_][rtl_][0]);      \
  } while (0)

#define MFMA_STEP(BV0, BV1, BUF) do {                                           \
    _Pragma("unroll")                                                           \
    for (int mf = 0; mf < 2; ++mf) {                                            \
      half8 av0 = *(const half8*)&sA[(BUF)][0][mf][lane * 8];                   \
      half8 av1 = *(const half8*)&sA[(BUF)][1][mf][lane * 8];                   \
      _Pragma("unroll")                                                         \
      for (int f = 0; f < 4; ++f) {                                             \
        acc0[mf][f] = __builtin_amdgcn_mfma_f32_16x16x32_f16(av0, BV0[f], acc0[mf][f], 0, 0, 0); \
        accM[mf][f] = __builtin_amdgcn_mfma_f32_16x16x32_f16(av0, BV1[f], accM[mf][f], 0, 0, 0); \
        accM[mf][f] = __builtin_amdgcn_mfma_f32_16x16x32_f16(av1, BV0[f], accM[mf][f], 0, 0, 0); \
      }                                                                         \
    }                                                                           \
  } while (0)

  for (int pass = 0; pass < 2; ++pass) {
    int jf0 = pass * 16 + w * 4;        // this wave's first jf frag
    size_t bBase = (size_t)(bnl * 32 + jf0) * 1280 + lane;  // 20 ks * 64

    f32x4 acc0[2][4], accM[2][4];
#pragma unroll
    for (int mf = 0; mf < 2; ++mf)
#pragma unroll
      for (int f = 0; f < 4; ++f) {
        acc0[mf][f] = (f32x4){0.f, 0.f, 0.f, 0.f};
        accM[mf][f] = (f32x4){0.f, 0.f, 0.f, 0.f};
      }

    half8 bE0[4], bE1[4], bO0[4], bO1[4];
    // prologue: B(0) -> E set; A(0) -> buf 0
#pragma unroll
    for (int f = 0; f < 4; ++f) bE0[f] = *(const half8*)&b0p[bBase + (size_t)f * 1280];
#pragma unroll
    for (int f = 0; f < 4; ++f) bE1[f] = *(const half8*)&b1p[bBase + (size_t)f * 1280];
    STAGE_A1(0, 0);

#pragma unroll 1
    for (int kk = 0; kk < 10; ++kk) {
      // ---- even step ks = 2kk: consumes bE + sA[0] ----
      __syncthreads();                 // A(2kk) landed; bE complete
      {
        size_t bo = bBase + (size_t)(2 * kk + 1) * 64;
#pragma unroll
        for (int f = 0; f < 4; ++f) bO0[f] = *(const half8*)&b0p[bo + (size_t)f * 1280];
#pragma unroll
        for (int f = 0; f < 4; ++f) bO1[f] = *(const half8*)&b1p[bo + (size_t)f * 1280];
      }
      STAGE_A1(2 * kk + 1, 1);
      __builtin_amdgcn_sched_barrier(0);   // pin: prefetch issued before MFMA
      MFMA_STEP(bE0, bE1, 0);

      // ---- odd step ks = 2kk+1: consumes bO + sA[1] ----
      __syncthreads();                 // A(2kk+1) landed; bO complete
      if (kk < 9) {
        size_t bo = bBase + (size_t)(2 * kk + 2) * 64;
#pragma unroll
        for (int f = 0; f < 4; ++f) bE0[f] = *(const half8*)&b0p[bo + (size_t)f * 1280];
#pragma unroll
        for (int f = 0; f < 4; ++f) bE1[f] = *(const half8*)&b1p[bo + (size_t)f * 1280];
        STAGE_A1(2 * kk + 2, 0);
      }
      __builtin_amdgcn_sched_barrier(0);   // pin: prefetch issued before MFMA
      MFMA_STEP(bO0, bO1, 1);
    }

    // fold this pass into LDS running argmax (j ascends with pass; strict >)
#pragma unroll
    for (int mf = 0; mf < 2; ++mf)
#pragma unroll
      for (int f = 0; f < 4; ++f) {
        int j = pass * 256 + w * 64 + f * 16 + (lane & 15);
        bool ok = (j < MS);
#pragma unroll
        for (int rg = 0; rg < 4; ++rg) {
          float v = ok ? (acc0[mf][f][rg] * CHI + accM[mf][f][rg] * CLO) : -1e30f;
          int ji = ok ? j : 0x7fffffff;
#pragma unroll
          for (int mk = 1; mk < 16; mk <<= 1) {
            float ov = __shfl_xor(v, mk);
            int oj = __shfl_xor(ji, mk);
            if (ov > v || (ov == v && oj < ji)) { v = ov; ji = oj; }
          }
          if ((lane & 15) == 0) {
            int row32 = mf * 16 + (lane >> 4) * 4 + rg;
            if (v > sV[w][row32]) { sV[w][row32] = v; sJ[w][row32] = ji; }
          }
        }
      }
  }
#undef STAGE_A1
#undef MFMA_STEP

  __syncthreads();
  // combine the 4 jw partials per row; single writer per row (wave 0)
  if (w == 0 && lane < 32) {
    int row32 = lane;
    float v = sV[0][row32];
    int ji = sJ[0][row32];
#pragma unroll
    for (int q4 = 1; q4 < 4; ++q4) {
      float ov = sV[q4][row32];
      int oj = sJ[q4][row32];
      if (ov > v || (ov == v && oj < ji)) { v = ov; ji = oj; }
    }
    int r = mt32 * 32 + row32;
    if (r < Q * HW) {
      int bq = bb * Q + r / 100, p = r % 100;
      size_t oo = (size_t)(bq * NWAY + n) * HW + p;
      cmax[oo] = v;
      carg[oo] = ji;
    }
  }
}

// ---------------------------------------------------------------------------
// Fallback fp32 simi kernel (used only if ws too small) — known-good.
// ---------------------------------------------------------------------------
#define TCF 32
#define TJF 64
__global__ __launch_bounds__(256) void simi_kernel(const float* __restrict__ s_xf,
                                                   const float* __restrict__ q_xf,
                                                   const float* __restrict__ invs,
                                                   const float* __restrict__ invq,
                                                   float* __restrict__ cmax,
                                                   int* __restrict__ carg) {
  int id = blockIdx.x;
  int n = id % NWAY;
  int bq = id / NWAY;
  int b = bq / Q;
  const float* qbase = q_xf + (size_t)bq * SLAB;
  const float* sbase = s_xf + (size_t)(b * 25 + n * KSHOT) * SLAB;
  const float* invqB = invq + bq * HW;
  const float* invsB = invs + (b * 2500 + n * MS);

  __shared__ __align__(16) float As[TCF][112];
  __shared__ __align__(16) float Bs[TCF][TJF];
  __shared__ float sInvQ[HW];
  __shared__ float sInvS[MS];

  int t = threadIdx.x;
  for (int i = t; i < HW; i += 256) sInvQ[i] = invqB[i];
  for (int i = t; i < MS; i += 256) sInvS[i] = invsB[i];

  int tj = t & 15, tm = t >> 4;
  float best[7];
  int bidx[7];
#pragma unroll
  for (int r = 0; r < 7; ++r) { best[r] = -1e30f; bidx[r] = 0; }

  for (int jt0 = 0; jt0 < MS; jt0 += TJF) {
    float acc[7][4];
#pragma unroll
    for (int r = 0; r < 7; ++r)
#pragma unroll
      for (int jj = 0; jj < 4; ++jj) acc[r][jj] = 0.f;
    for (int c0 = 0; c0 < C; c0 += TCF) {
      __syncthreads();
      for (int i = t; i < TCF * HW; i += 256) {
        int p = i % HW;
        As[i / HW][p] = qbase[c0 * HW + i] * sInvQ[p];
      }
      for (int i = t; i < TCF * TJF; i += 256) {
        int cc = i / TJF, jj = i % TJF;
        int j = jt0 + jj;
        float v = 0.f;
        if (j < MS) v = sbase[(j / 100) * SLAB + (c0 + cc) * 100 + (j % 100)] * sInvS[j];
        Bs[cc][jj] = v;
      }
      __syncthreads();
#pragma unroll
      for (int cc = 0; cc < TCF; ++cc) {
        float4 bv = *(const float4*)&Bs[cc][tj * 4];
#pragma unroll
        for (int r = 0; r < 7; ++r) {
          float a = As[cc][tm * 7 + r];
          acc[r][0] = fmaf(a, bv.x, acc[r][0]);
          acc[r][1] = fmaf(a, bv.y, acc[r][1]);
          acc[r][2] = fmaf(a, bv.z, acc[r][2]);
          acc[r][3] = fmaf(a, bv.w, acc[r][3]);
        }
      }
    }
#pragma unroll
    for (int r = 0; r < 7; ++r)
#pragma unroll
      for (int jj = 0; jj < 4; ++jj) {
        int j = jt0 + tj * 4 + jj;
        float v = acc[r][jj];
        if (j < MS && v > best[r]) { best[r] = v; bidx[r] = j; }
      }
  }
#pragma unroll
  for (int r = 0; r < 7; ++r)
#pragma unroll
    for (int mask = 1; mask < 16; mask <<= 1) {
      float ov = __shfl_xor(best[r], mask);
      int oi = __shfl_xor(bidx[r], mask);
      if (ov > best[r] || (ov == best[r] && oi < bidx[r])) { best[r] = ov; bidx[r] = oi; }
    }
  if (tj == 0)
#pragma unroll
    for (int r = 0; r < 7; ++r) {
      int m = tm * 7 + r;
      if (m < HW) {
        cmax[(size_t)(bq * NWAY + n) * HW + m] = best[r];
        carg[(size_t)(bq * NWAY + n) * HW + m] = bidx[r];
      }
    }
}

// ---------------------------------------------------------------------------
// K4: per-(b,qi) DMNN mask + query_value + per-query loss.
// ---------------------------------------------------------------------------
__global__ __launch_bounds__(128) void mask_loss_kernel(const float* __restrict__ cmax,
                                                        const int* __restrict__ carg,
                                                        const int* __restrict__ query_y,
                                                        float* __restrict__ lossv) {
  int bq = blockIdx.x;
  int t = threadIdx.x;
  __shared__ float sDiff[HW];
  __shared__ int sNear[HW];
  __shared__ float sCm[NWAY][HW];
  __shared__ float red[128];

  if (t < HW) {
    float cm[NWAY];
#pragma unroll
    for (int nn = 0; nn < NWAY; ++nn) {
      cm[nn] = cmax[(size_t)(bq * NWAY + nn) * HW + t];
      sCm[nn][t] = cm[nn];
    }
    float v0 = -1e30f, v1 = -1e30f;
#pragma unroll
    for (int nn = 0; nn < NWAY; ++nn) {
      float v = cm[nn];
      if (v > v0) { v1 = v0; v0 = v; }
      else if (v > v1) { v1 = v; }
    }
    sDiff[t] = v0 - v1;
    float gb = -1e30f;
    int gn = 0;
#pragma unroll
    for (int nn = 0; nn < NWAY; ++nn)
      if (cm[nn] > gb) { gb = cm[nn]; gn = nn; }
    sNear[t] = gn * MS + carg[(size_t)(bq * NWAY + gn) * HW + t];
  }
  __syncthreads();

  bool msk = false;
  if (t < HW) {
    int j = sNear[t];
    int wn = 0;
    float wv = -1.f;
    for (int mp = 0; mp < HW; ++mp) {
      float v = (sNear[mp] == j) ? sDiff[mp] : 0.f;
      if (v > wv) { wv = v; wn = mp; }
    }
    msk = (wn == t);
  }

  float qv[NWAY];
#pragma unroll
  for (int nn = 0; nn < NWAY; ++nn) {
    __syncthreads();
    red[t] = (t < HW && msk) ? sCm[nn][t] : 0.f;
    __syncthreads();
    for (int s = 64; s > 0; s >>= 1) {
      if (t < s) red[t] += red[t + s];
      __syncthreads();
    }
    qv[nn] = red[0];
  }

  if (t == 0) {
    float logits[NWAY], mx = -1e30f;
#pragma unroll
    for (int nn = 0; nn < NWAY; ++nn) {
      logits[nn] = qv[nn] / 0.2f;
      mx = fmaxf(mx, logits[nn]);
    }
    float se = 0.f;
#pragma unroll
    for (int nn = 0; nn < NWAY; ++nn) se += expf(logits[nn] - mx);
    float lse = mx + logf(se);
    int label = query_y[bq];
    lossv[bq] = -(logits[label] - lse);
  }
}

__global__ __launch_bounds__(512) void finalize_kernel(const float* __restrict__ lossv,
                                                       float* __restrict__ out) {
  __shared__ float red[512];
  int t = threadIdx.x;
  red[t] = (t < NBQ) ? lossv[t] : 0.f;
  __syncthreads();
  for (int s = 256; s > 0; s >>= 1) {
    if (t < s) red[t] += red[t + s];
    __syncthreads();
  }
  if (t == 0) out[0] = red[0] / (float)NBQ;
}

extern "C" void kernel_launch(void* const* d_in, const int* in_sizes, int n_in,
                              void* d_out, int out_size, void* d_ws, size_t ws_size,
                              hipStream_t stream) {
  const float* s_xf = (const float*)d_in[0];
  const float* q_xf = (const float*)d_in[2];
  const int* query_y = (const int*)d_in[3];

  float* ws = (float*)d_ws;
  float* invs = ws;
  float* invq = ws + 10000;
  float* cmax = ws + 40000;
  int* carg = (int*)(ws + 190000);
  float* lossv = ws + 340000;

  norm_kernel<<<400, 256, 0, stream>>>(s_xf, q_xf, invs, invq);

  const size_t SP_ALL = 3276800, SP_B = 819200, QS_B = 2416640;

  if (ws_size >= NEED_ALL) {
    uint4* S0 = (uint4*)(ws + WS_BASE);
    uint4* S1 = (uint4*)(ws + WS_BASE + SP_ALL);
    uint4* Q0 = (uint4*)(ws + WS_BASE + 2 * SP_ALL);
    uint4* Q1 = (uint4*)(ws + WS_BASE + 2 * SP_ALL + 4 * QS_B);
    convs_kernel<<<S_CHUNKS_ALL / 256, 256, 0, stream>>>(s_xf, invs, S0, S1, 0);
    convq_kernel<<<4 * A_CHUNKS_B / 256, 256, 0, stream>>>(q_xf, invq, Q0, Q1, 0);
    gemm_kernel<<<4720, 256, 0, stream>>>(Q0, Q1, S0, S1,
                                          cmax, carg, 0, A_CHUNKS_B, 0, 0);
  } else if (ws_size >= NEED_PERB) {
    uint4* S0 = (uint4*)(ws + WS_BASE);
    uint4* S1 = (uint4*)(ws + WS_BASE + SP_ALL);
    uint4* Q0 = (uint4*)(ws + WS_BASE + 2 * SP_ALL);
    uint4* Q1 = (uint4*)(ws + WS_BASE + 2 * SP_ALL + QS_B);
    convs_kernel<<<S_CHUNKS_ALL / 256, 256, 0, stream>>>(s_xf, invs, S0, S1, 0);
    for (int b = 0; b < 4; ++b) {
      convq_kernel<<<A_CHUNKS_B / 256, 256, 0, stream>>>(q_xf, invq, Q0, Q1, b);
      gemm_kernel<<<1184, 256, 0, stream>>>(Q0, Q1, S0, S1,
                                            cmax, carg, b, 0, 0, 1);
    }
  } else if (ws_size >= NEED_PERB2) {
    uint4* S0 = (uint4*)(ws + WS_BASE);
    uint4* S1 = (uint4*)(ws + WS_BASE + SP_B);
    uint4* Q0 = (uint4*)(ws + WS_BASE + 2 * SP_B);
    uint4* Q1 = (uint4*)(ws + WS_BASE + 2 * SP_B + QS_B);
    for (int b = 0; b < 4; ++b) {
      convs_kernel<<<S_CHUNKS_B / 256, 256, 0, stream>>>(s_xf, invs, S0, S1, b * 5);
      convq_kernel<<<A_CHUNKS_B / 256, 256, 0, stream>>>(q_xf, invq, Q0, Q1, b);
      gemm_kernel<<<1184, 256, 0, stream>>>(Q0, Q1, S0, S1,
                                            cmax, carg, b, 0, b * 5, 1);
    }
  } else {
    simi_kernel<<<1500, 256, 0, stream>>>(s_xf, q_xf, invs, invq, cmax, carg);
  }

  mask_loss_kernel<<<NBQ, 128, 0, stream>>>(cmax, carg, query_y, lossv);
  finalize_kernel<<<1, 512, 0, stream>>>(lossv, (float*)d_out);
}